// Round 6
// baseline (2743.382 us; speedup 1.0000x reference)
//
#include <hip/hip_runtime.h>
#include <stdint.h>
#include <math.h>

#define NIN    784
#define H1     100
#define H2     10
#define BATCH  4096
#define KC     28        // K-chunk cols; 784 = 28*28
#define NCH    28
#define KCP    32        // xib row stride (floats)
#define RT     16        // rows per block
#define NSTEP  99        // layer2 t=0..98; layer1 t=0..97

typedef float v2f __attribute__((ext_vector_type(2)));

// ---- Threefry-2x32 (jax partitionable path, verified R4/R5) ----
__device__ __forceinline__ void threefry2x32(uint32_t k0, uint32_t k1,
                                             uint32_t x0, uint32_t x1,
                                             uint32_t& o0, uint32_t& o1) {
    uint32_t ks2 = k0 ^ k1 ^ 0x1BD11BDAu;
    x0 += k0; x1 += k1;
#define TFR(r) { x0 += x1; x1 = (x1 << (r)) | (x1 >> (32 - (r))); x1 ^= x0; }
    TFR(13) TFR(15) TFR(26) TFR(6)  x0 += k1;  x1 += ks2 + 1u;
    TFR(17) TFR(29) TFR(16) TFR(24) x0 += ks2; x1 += k0 + 2u;
    TFR(13) TFR(15) TFR(26) TFR(6)  x0 += k0;  x1 += k1 + 3u;
    TFR(17) TFR(29) TFR(16) TFR(24) x0 += k1;  x1 += ks2 + 4u;
    TFR(13) TFR(15) TFR(26) TFR(6)  x0 += ks2; x1 += k0 + 5u;
#undef TFR
    o0 = x0; o1 = x1;
}

__device__ __forceinline__ float u01(uint32_t b) {
    return __uint_as_float((b >> 9) | 0x3f800000u) - 1.0f;
}

__global__ void transpose_w1(const float* __restrict__ W1, float* __restrict__ w1t) {
    int idx = blockIdx.x * 256 + threadIdx.x;
    if (idx < NIN * H1) {
        int h = idx / NIN, jj = idx - h * NIN;
        w1t[idx] = W1[jj * H1 + h];
    }
}

// GEMM over quads [Q0,Q1) of one chunk: 8 rows x (h0,h1), packed-f32 FMA.
template<int Q0, int Q1>
__device__ __forceinline__ void gemm_quads(const float* __restrict__ wb,   // wt[buf]
                                           const float* __restrict__ xb,   // xib row base for rg
                                           int h0off, int h1off,
                                           v2f* __restrict__ acc0, v2f* __restrict__ acc1) {
#pragma unroll
    for (int jq = Q0; jq < Q1; ++jq) {
        float4 w0  = *(const float4*)&wb[h0off + jq * 4];
        float4 w1q = *(const float4*)&wb[h1off + jq * 4];
        v2f w0a = {w0.x, w0.y},  w0b = {w0.z, w0.w};
        v2f w1a = {w1q.x, w1q.y}, w1b = {w1q.z, w1q.w};
#pragma unroll
        for (int r = 0; r < 8; ++r) {
            float4 xq = *(const float4*)&xb[r * KCP + jq * 4];
            v2f xa = {xq.x, xq.y}, xzw = {xq.z, xq.w};
            acc0[r] = __builtin_elementwise_fma(xa,  w0a, acc0[r]);
            acc0[r] = __builtin_elementwise_fma(xzw, w0b, acc0[r]);
            acc1[r] = __builtin_elementwise_fma(xa,  w1a, acc1[r]);
            acc1[r] = __builtin_elementwise_fma(xzw, w1b, acc1[r]);
        }
    }
}

__global__ __launch_bounds__(1024)
void spiking_net_kernel(const float* __restrict__ x,
                        const float* __restrict__ w1t,
                        const float* __restrict__ b1,
                        const float* __restrict__ W2,
                        const float* __restrict__ b2,
                        float* __restrict__ out) {
    __shared__ __align__(16) float    wt[2][KC * H1];    // 22400 B
    __shared__ __align__(16) float    xib[2][RT * KCP];  //  4096 B
    __shared__ __align__(16) float    o1s[RT * H1];      //  6400 B
    __shared__ __align__(16) float    w2t[H2 * H1];      //  4000 B
    __shared__ __align__(16) float    red[3 * RT * 128]; // 24576 B
    __shared__ __align__(16) float    sums[RT * H2];     //   640 B
    __shared__           uint32_t keys[200];             //   800 B  (62912 B total)

    const int tid  = threadIdx.x;
    const int wv   = tid >> 6;
    const int lane = tid & 63;
    const int row0 = blockIdx.x * RT;

    // roles: waves 0-7 GEMM (q = wv&3 quarter, rg = wv>>2 row-group of 8 rows)
    //        waves 8-15 hash + stage
    const bool isg = (wv < 8);
    const int  q   = wv & 3;
    const int  rg  = (wv >> 2) & 1;

    if (tid < 100) {
        uint32_t y0, y1;
        threefry2x32(0u, 42u, 0u, (uint32_t)tid, y0, y1);
        keys[2 * tid] = y0; keys[2 * tid + 1] = y1;
    }
    for (int i = tid; i < H2 * H1; i += 1024) {
        int cc = i / H1, k = i - cc * H1;
        w2t[i] = W2[k * H2 + cc];
    }
    for (int i = tid; i < RT * H1; i += 1024) o1s[i] = 0.0f;

    // GEMM lanes: h0 = lane, h1 = lane+64 (lanes >= 36 idle on h1)
    const int  h0   = lane;
    const bool h1v  = (lane < H1 - 64);
    const int  h1   = h1v ? (64 + lane) : (H1 - 1);
    const int  h0off = h0 * KC;
    const int  h1off = h1 * KC;
    const float b1_0 = b1[h0];
    const float b1_1 = b1[h1];
    float i1[8][2];
#pragma unroll
    for (int r = 0; r < 8; ++r) { i1[r][0] = 0.f; i1[r][1] = 0.f; }

    // ---- hoisted per-thread staging/hash indexing (chunk-invariant) ----
    // stage: hash waves move 700 float4 quads of the W1 chunk
    const int  hw   = wv - 8;                     // 0..7 for hash waves
    const int  sidx = hw * 64 + lane;             // 0..511
    int  sa_lds = 0, sa_src = 0, sb_lds = 0, sb_src = 0;
    bool sb_v = false;
    if (!isg) {
        int ha = sidx / 7, ja = sidx - ha * 7;
        sa_lds = ha * KC + ja * 4;
        sa_src = ha * NIN + ja * 4;
        int qb = sidx + 512;                      // 512..1023; valid < 700
        sb_v = (qb < KC * H1 / 4);
        int hb = qb / 7, jb = qb - hb * 7;
        sb_lds = hb * KC + jb * 4;
        sb_src = hb * NIN + jb * 4;
    }
    // hash: e = hw*56+lane (lane<56), r = e/28, jj = e%28
    const bool hact = (!isg) && (lane < 56);
    int  he_r = 0, he_jj = 0, hx_base = 0, hl_off = 0;
    if (hact) {
        int e = hw * 56 + lane;
        he_r  = e / KC;
        he_jj = e - he_r * KC;
        hx_base = (row0 + he_r) * NIN + he_jj;    // + c*KC per chunk
        hl_off  = he_r * KCP + he_jj;
    }

    // layer2: thread (r2, c2) for tid < 160 (GEMM waves 0-2)
    const int  r2    = tid / 10;
    const int  c2    = tid - r2 * 10;
    const bool l2act = (tid < RT * H2);
    const float b2r  = l2act ? b2[c2] : 0.0f;
    float i2 = 0.0f, sum2 = 0.0f;

    __syncthreads();

    auto stage = [&](int c, int b) {
        *(float4*)&wt[b][sa_lds] = *(const float4*)&w1t[sa_src + c * KC];
        if (sb_v) *(float4*)&wt[b][sb_lds] = *(const float4*)&w1t[sb_src + c * KC];
    };
    auto genxi = [&](int c, int b, uint32_t k0, uint32_t k1) {
        if (hact) {
            uint32_t ctr = (uint32_t)(hx_base + c * KC);
            uint32_t y0, y1;
            threefry2x32(k0, k1, 0u, ctr, y0, y1);
            xib[b][hl_off] = u01(y0 ^ y1) * x[hx_base + c * KC];
        }
    };

    v2f acc0[8], acc1[8];
    const float* const xbase = &xib[0][0];   // buffer stride RT*KCP floats

    for (int t = 0; t < NSTEP; ++t) {
        const uint32_t k0 = keys[2 * t], k1 = keys[2 * t + 1];
        const bool dol1 = (t < 98);

        // ---- phase A: hash waves stage chunk0; GEMM waves zero acc + layer2 ----
        if (dol1 && !isg) { stage(0, 0); genxi(0, 0, k0, k1); }
        if (isg) {
#pragma unroll
            for (int r = 0; r < 8; ++r) { acc0[r] = (v2f){0.f, 0.f}; acc1[r] = (v2f){0.f, 0.f}; }
            if (l2act) {
                const float* orow = &o1s[r2 * H1];
                const float* wrow = &w2t[c2 * H1];
                float a = 0.0f;
#pragma unroll
                for (int k = 0; k < H1; k += 4) {
                    float4 ov = *(const float4*)&orow[k];
                    float4 wq = *(const float4*)&wrow[k];
                    a = fmaf(ov.x, wq.x, a); a = fmaf(ov.y, wq.y, a);
                    a = fmaf(ov.z, wq.z, a); a = fmaf(ov.w, wq.w, a);
                }
                float inner2 = (a + b2r) + i2 * 0.9f;
                float outer2 = fmaxf(inner2 - 1.0f, 0.0f);
                inner2 = (outer2 > 0.0f) ? (inner2 - 1.5f * inner2) : inner2;
                i2 = inner2;
                if (t >= 19) sum2 += inner2;
            }
        }
        __syncthreads();

        if (dol1) {
            for (int c = 0; c < NCH; ++c) {
                const int b = c & 1;
                if (!isg) {
                    if (c + 1 < NCH) { stage(c + 1, b ^ 1); genxi(c + 1, b ^ 1, k0, k1); }
                } else {
                    const float* wb = wt[b];
                    const float* xb = xbase + b * (RT * KCP) + rg * (8 * KCP);
                    switch (q) {
                        case 0: gemm_quads<0, 2>(wb, xb, h0off, h1off, acc0, acc1); break;
                        case 1: gemm_quads<2, 4>(wb, xb, h0off, h1off, acc0, acc1); break;
                        case 2: gemm_quads<4, 6>(wb, xb, h0off, h1off, acc0, acc1); break;
                        default: gemm_quads<6, 7>(wb, xb, h0off, h1off, acc0, acc1); break;
                    }
                }
                __syncthreads();
            }
            // ---- publish partials (quarters 1-3) ----
            if (isg && q > 0) {
#pragma unroll
                for (int r = 0; r < 8; ++r) {
                    red[(q - 1) * (RT * 128) + (8 * rg + r) * 128 + lane]      = acc0[r].x + acc0[r].y;
                    red[(q - 1) * (RT * 128) + (8 * rg + r) * 128 + 64 + lane] = acc1[r].x + acc1[r].y;
                }
            }
            __syncthreads();
            // ---- reduce + neuron update (quarter-0 waves own state) ----
            if (isg && q == 0) {
#pragma unroll
                for (int r = 0; r < 8; ++r) {
                    float a0 = acc0[r].x + acc0[r].y;
                    float a1 = acc1[r].x + acc1[r].y;
#pragma unroll
                    for (int p = 0; p < 3; ++p) {
                        a0 += red[p * (RT * 128) + (8 * rg + r) * 128 + lane];
                        a1 += red[p * (RT * 128) + (8 * rg + r) * 128 + 64 + lane];
                    }
                    float in0  = (a0 + b1_0) + i1[r][0] * 0.9f;
                    float out0 = fmaxf(in0 - 1.0f, 0.0f);
                    in0 = (out0 > 0.0f) ? (in0 - 1.5f * in0) : in0;
                    i1[r][0] = in0;
                    o1s[(8 * rg + r) * H1 + h0] = out0;

                    float in1  = (a1 + b1_1) + i1[r][1] * 0.9f;
                    float out1 = fmaxf(in1 - 1.0f, 0.0f);
                    in1 = (out1 > 0.0f) ? (in1 - 1.5f * in1) : in1;
                    i1[r][1] = in1;
                    if (h1v) o1s[(8 * rg + r) * H1 + h1] = out1;
                }
            }
        }
        __syncthreads();
    }

    // ---- epilogue: log_softmax ----
    if (l2act) sums[r2 * H2 + c2] = sum2;
    __syncthreads();
    if (l2act) {
        float m = -INFINITY;
#pragma unroll
        for (int cc = 0; cc < H2; ++cc) m = fmaxf(m, sums[r2 * H2 + cc]);
        float s = 0.0f;
#pragma unroll
        for (int cc = 0; cc < H2; ++cc) s += expf(sums[r2 * H2 + cc] - m);
        out[(row0 + r2) * H2 + c2] = sum2 - m - logf(s);
    }
}

extern "C" void kernel_launch(void* const* d_in, const int* in_sizes, int n_in,
                              void* d_out, int out_size, void* d_ws, size_t ws_size,
                              hipStream_t stream) {
    const float* x  = (const float*)d_in[0];
    const float* W1 = (const float*)d_in[1];
    const float* b1 = (const float*)d_in[2];
    const float* W2 = (const float*)d_in[3];
    const float* b2 = (const float*)d_in[4];
    float* out = (float*)d_out;
    float* w1t = (float*)d_ws;                      // 313.6 KB scratch

    hipLaunchKernelGGL(transpose_w1, dim3((NIN * H1 + 255) / 256), dim3(256), 0, stream,
                       W1, w1t);
    // 256 blocks x 1024 threads; waves 0-7 GEMM (2 rg x 4 quarters), 8-15 hash+stage
    hipLaunchKernelGGL(spiking_net_kernel, dim3(BATCH / RT), dim3(1024), 0, stream,
                       x, w1t, b1, W2, b2, out);
}